// Round 9
// baseline (235.860 us; speedup 1.0000x reference)
//
#include <hip/hip_runtime.h>
#include <stdint.h>

// Problem constants (B=4, N=16384, NP=4096) — ALL TENSORS FLOAT32.
#define QT   65536
#define NPTS 4096
#define C1   128
#define C2   256
#define CIN  384
#define COUT 128

typedef _Float16 f16;
typedef __attribute__((ext_vector_type(8))) _Float16 f16x8;
typedef __attribute__((ext_vector_type(4))) float f32x4;

// Pre-packed (per-launch) weights, f16 in MFMA B-fragment order:
//   idx = ((kcb*NCB + cb)*64 + lane)*8 + e
//   holds W[(kcb*32 + (lane>>4)*8 + e) * N + cb*16 + (lane&15)]
// -> a wave's fragment (kcb, cb) is one contiguous 1KB block; lane reads
//    16B at lane*16 -> single global_load_dwordx4, L2-resident.
__device__ __attribute__((aligned(16))) f16 g_w1p[12 * 16 * 64 * 8];
__device__ __attribute__((aligned(16))) f16 g_w2p[8 * 16 * 64 * 8];
__device__ __attribute__((aligned(16))) f16 g_w3p[8 * 8 * 64 * 8];
// Candidate table: (x, y, z, |p|^2) per xyz2 point, per batch. 256 KB,
// L2-resident. Read via wave-uniform pointer in the scan (scalar pipe).
__device__ __attribute__((aligned(16))) float4 g_cand[4 * NPTS];

// packW4: one iteration packs 4 lanes (consecutive cols) of one fragment,
// reading float4 from W (coalesced within the 4-col group).
__device__ inline void packW4(const float* __restrict__ W, f16* __restrict__ dst,
                              int i, int N, int NCB) {
  const int g = i & 3, quad = (i >> 2) & 3, cbk = i >> 4;
  const int cb = cbk % NCB, kcb = cbk / NCB;
  const int col = cb * 16 + g * 4;
  const int k0 = kcb * 32 + quad * 8;
  f16x8 o[4];
#pragma unroll
  for (int e = 0; e < 8; ++e) {
    float4 v = *(const float4*)(W + (size_t)(k0 + e) * N + col);
    o[0][e] = (f16)v.x; o[1][e] = (f16)v.y; o[2][e] = (f16)v.z; o[3][e] = (f16)v.w;
  }
  f16* base = dst + ((size_t)cbk * 64 + quad * 16 + g * 4) * 8;
#pragma unroll
  for (int j = 0; j < 4; ++j) *(f16x8*)(base + j * 8) = o[j];
}

__global__ __launch_bounds__(256) void prep(
    const float* __restrict__ xyz2, const float* __restrict__ W1,
    const float* __restrict__ W2,   const float* __restrict__ W3) {
  const int tid = blockIdx.x * 256 + threadIdx.x;
  const int nthr = gridDim.x * 256;
  for (int i = tid; i < 4 * NPTS; i += nthr) {
    const float* p = xyz2 + (size_t)i * 3;
    float x = p[0], y = p[1], z = p[2];
    g_cand[i] = make_float4(x, y, z, fmaf(x, x, fmaf(y, y, z * z)));
  }
  for (int i = tid; i < 12 * 16 * 16; i += nthr) packW4(W1, g_w1p, i, 256, 16);
  for (int i = tid; i < 8 * 16 * 16; i += nthr) packW4(W2, g_w2p, i, 256, 16);
  for (int i = tid; i < 8 * 8 * 16; i += nthr) packW4(W3, g_w3p, i, 128, 8);
}

__device__ inline uint32_t umin(uint32_t a, uint32_t b) { return a < b ? a : b; }
__device__ inline uint32_t med3u(uint32_t a, uint32_t b, uint32_t c) {
  uint32_t d;
  asm("v_med3_u32 %0, %1, %2, %3" : "=v"(d) : "v"(a), "v"(b), "v"(c));
  return d;
}

// LDS overlay (phases strictly barrier-separated) — 35840 B => 4 blocks/CU:
//  Phase A: dmpD f64[8][64][3]     @0      (12288)  per-wave top-3 dists
//           dmpI i32[8][64][3]     @12288  (6144)   per-wave top-3 idx
//  persist: wv   f32[64][4]        @33792  (1024)
//           iv   i32[64][4]        @34816  (1024)   end 35840
//  Phase B: Xs f16[64][264]        @0      (33792)  interp half of X only
//           Hs f16[64][264]        @0      (33792)  (H1, then H2)
// f1 half of X is read directly from global f32 in L1 (same cast point).
#define XS_STRIDE 264
#define HS_STRIDE 264
#define DMPD_OFF 0
#define DMPI_OFF 12288
#define WV_OFF 33792
#define IV_OFF 34816
#define SMEM_BYTES 35840

__global__ __launch_bounds__(512) void fused_fp(
    const float* __restrict__ xyz1, const float* __restrict__ xyz2,
    const float* __restrict__ f1,   const float* __restrict__ f2,
    const float* __restrict__ W1,   const float* __restrict__ b1,
    const float* __restrict__ W2,   const float* __restrict__ b2,
    const float* __restrict__ W3,   const float* __restrict__ b3,
    float* __restrict__ out)
{
  __shared__ __align__(16) char smem[SMEM_BYTES];
  double*   dmpD = (double*)(smem + DMPD_OFF);  // [8][64][3]
  int*      dmpI = (int*)(smem + DMPI_OFF);     // [8][64][3]
  float*    wvp  = (float*)(smem + WV_OFF);     // [64][4]
  int*      ivp  = (int*)(smem + IV_OFF);       // [64][4]
  f16*      Xs   = (f16*)smem;                  // [64][XS_STRIDE] (interp)
  f16*      Hs   = (f16*)smem;                  // [64][HS_STRIDE]

  const int t = threadIdx.x;
  const int r = t & 63;              // query row within block / lane id
  const int w = t >> 6;              // wave id 0..7
  const int qb = blockIdx.x * 64;
  const int batch = qb >> 14;        // 16384 queries per batch
  const float* xz2b = xyz2 + (size_t)batch * NPTS * 3;
  const float* f2b  = f2   + (size_t)batch * NPTS * C2;

  // ======================= Phase A: exact 3-NN =======================
  // Per-lane top-5 of packed keys over this wave's 512-candidate slice:
  //   e   = fma(nx,cx, fma(ny,cy, fma(nz,cz, |p|^2))) + (|q|^2 + 0.05)
  //   key = (bits(e) & 0xFFFFF000) | idx        (compiler fuses to v_and_or)
  // +0.05 bias: e > 0 always, u32 order == float order; monotone add.
  // 12 dropped mantissa bits = 4.9e-4 relative quantization, absorbed by
  // depth-5 margin + exact f64 rescore (proven r2/r6/r8).
  const int q = qb + r;
  const float qx = xyz1[q * 3], qy = xyz1[q * 3 + 1], qz = xyz1[q * 3 + 2];
  const float nx = -2.f * qx, ny = -2.f * qy, nz = -2.f * qz;
  const float sq1q = qx * qx + qy * qy + qz * qz;

  uint32_t k0 = ~0u, k1 = ~0u, k2 = ~0u, k3 = ~0u, k4 = ~0u;

  auto ins5 = [&](uint32_t c) {
    uint32_t n0 = umin(k0, c);
    uint32_t n1 = med3u(k0, k1, c);
    uint32_t n2 = med3u(k1, k2, c);
    uint32_t n3 = med3u(k2, k3, c);
    uint32_t n4 = med3u(k3, k4, c);
    k0 = n0; k1 = n1; k2 = n2; k3 = n3; k4 = n4;
  };
  auto packk = [&](float e, uint32_t idx) -> uint32_t {
    return (__builtin_bit_cast(uint32_t, e) & 0xFFFFF000u) | idx;
  };

  {
    const int wu = __builtin_amdgcn_readfirstlane(w);   // force SGPR-uniform
    const float4* __restrict__ cp = g_cand + (batch << 12) + (wu << 9);
    const uint32_t abase = (uint32_t)(wu << 9);
    const float sbias = sq1q + 0.05f;
    #pragma unroll 2
    for (int m = 0; m < 512; m += 4) {
      float4 c0 = cp[m], c1 = cp[m + 1], c2 = cp[m + 2], c3 = cp[m + 3];
      float e0 = fmaf(nx, c0.x, fmaf(ny, c0.y, fmaf(nz, c0.z, c0.w))) + sbias;
      float e1 = fmaf(nx, c1.x, fmaf(ny, c1.y, fmaf(nz, c1.z, c1.w))) + sbias;
      float e2 = fmaf(nx, c2.x, fmaf(ny, c2.y, fmaf(nz, c2.z, c2.w))) + sbias;
      float e3 = fmaf(nx, c3.x, fmaf(ny, c3.y, fmaf(nz, c3.z, c3.w))) + sbias;
      ins5(packk(e0, abase + m));
      ins5(packk(e1, abase + m + 1));
      ins5(packk(e2, abase + m + 2));
      ins5(packk(e3, abase + m + 3));
    }
  }

  // ---- Stage 1 (ALL waves, parallel): exact f64 rescore of this wave's
  // own 5 register-held survivors -> per-wave top-3 (d, idx), total order
  // (d, then low idx).
  {
    const double x1 = (double)qx, y1 = (double)qy, z1 = (double)qz;
    const double sq1 = x1 * x1 + y1 * y1 + z1 * z1;
    double d0 = 1e300, d1 = 1e300, d2 = 1e300;
    int j0 = 0, j1 = 0, j2 = 0;
    uint32_t sv[5] = {k0, k1, k2, k3, k4};
    #pragma unroll
    for (int s = 0; s < 5; ++s) {
      int idx = (int)(sv[s] & (NPTS - 1));
      const float* p2 = xz2b + (size_t)idx * 3;
      double x2 = (double)p2[0], y2 = (double)p2[1], z2 = (double)p2[2];
      double d = sq1 + (x2 * x2 + y2 * y2 + z2 * z2)
                     - 2.0 * (x1 * x2 + y1 * y2 + z1 * z2);
      bool c2 = (d < d2) || (d == d2 && idx < j2);
      bool c1 = (d < d1) || (d == d1 && idx < j1);
      bool c0 = (d < d0) || (d == d0 && idx < j0);
      d2 = c1 ? d1 : (c2 ? d : d2);  j2 = c1 ? j1 : (c2 ? idx : j2);
      d1 = c0 ? d0 : (c1 ? d : d1);  j1 = c0 ? j0 : (c1 ? idx : j1);
      d0 = c0 ? d : d0;              j0 = c0 ? idx : j0;
    }
    const int base = (w * 64 + r) * 3;
    dmpD[base]     = d0;  dmpI[base]     = j0;
    dmpD[base + 1] = d1;  dmpI[base + 1] = j1;
    dmpD[base + 2] = d2;  dmpI[base + 2] = j2;
  }
  __syncthreads();

  // ---- Stage 2 (wave 0): merge the 24 (d, idx) pairs from LDS.
  // top3(union) == top3(union of per-group top3) under the same total order
  // -> bit-identical to the single-stage 40-rescore.
  if (w == 0) {
    double d0 = 1e300, d1 = 1e300, d2 = 1e300;
    int j0 = 0, j1 = 0, j2 = 0;
    #pragma unroll
    for (int w2 = 0; w2 < 8; ++w2) {
      #pragma unroll
      for (int s = 0; s < 3; ++s) {
        const int base = (w2 * 64 + r) * 3 + s;
        double d = dmpD[base];
        int idx  = dmpI[base];
        bool c2 = (d < d2) || (d == d2 && idx < j2);
        bool c1 = (d < d1) || (d == d1 && idx < j1);
        bool c0 = (d < d0) || (d == d0 && idx < j0);
        d2 = c1 ? d1 : (c2 ? d : d2);  j2 = c1 ? j1 : (c2 ? idx : j2);
        d1 = c0 ? d0 : (c1 ? d : d1);  j1 = c0 ? j0 : (c1 ? idx : j1);
        d0 = c0 ? d : d0;              j0 = c0 ? idx : j0;
      }
    }
    float e0 = fmaxf((float)d0, 1e-10f);
    float e1 = fmaxf((float)d1, 1e-10f);
    float e2 = fmaxf((float)d2, 1e-10f);
    float r0 = 1.f / e0, r1 = 1.f / e1, r2 = 1.f / e2;
    float inv = 1.f / (r0 + r1 + r2);
    wvp[r * 4 + 0] = r0 * inv; wvp[r * 4 + 1] = r1 * inv;
    wvp[r * 4 + 2] = r2 * inv; wvp[r * 4 + 3] = 0.f;
    ivp[r * 4 + 0] = j0; ivp[r * 4 + 1] = j1; ivp[r * 4 + 2] = j2; ivp[r * 4 + 3] = 0;
  }
  __syncthreads();

  // ====== Build interp half of X once per block (f16 in LDS, cols 0..255
  // of Xs == X cols 128..383). f32 weighted sum then one f16 cast —
  // identical numerics to r2/r6/r8 (passing). dmp region now dead (overlay).
  {
    const int row = t >> 3, c = t & 7;
    f16* xr = Xs + row * XS_STRIDE;
    const float w0 = wvp[row * 4 + 0], w1 = wvp[row * 4 + 1], w2 = wvp[row * 4 + 2];
    const float* p0 = f2b + (size_t)(ivp[row * 4 + 0] & (NPTS - 1)) * C2;
    const float* p1 = f2b + (size_t)(ivp[row * 4 + 1] & (NPTS - 1)) * C2;
    const float* p2 = f2b + (size_t)(ivp[row * 4 + 2] & (NPTS - 1)) * C2;
    #pragma unroll
    for (int ch = 0; ch < 4; ++ch) {
      const int col = ch * 64 + c * 8;
      float4 a0 = *(const float4*)(p0 + col), b0 = *(const float4*)(p0 + col + 4);
      float4 a1 = *(const float4*)(p1 + col), b1v = *(const float4*)(p1 + col + 4);
      float4 a2 = *(const float4*)(p2 + col), b2v = *(const float4*)(p2 + col + 4);
      f16x8 o;
      o[0] = (f16)(w0 * a0.x + w1 * a1.x + w2 * a2.x);
      o[1] = (f16)(w0 * a0.y + w1 * a1.y + w2 * a2.y);
      o[2] = (f16)(w0 * a0.z + w1 * a1.z + w2 * a2.z);
      o[3] = (f16)(w0 * a0.w + w1 * a1.w + w2 * a2.w);
      o[4] = (f16)(w0 * b0.x + w1 * b1v.x + w2 * b2v.x);
      o[5] = (f16)(w0 * b0.y + w1 * b1v.y + w2 * b2v.y);
      o[6] = (f16)(w0 * b0.z + w1 * b1v.z + w2 * b2v.z);
      o[7] = (f16)(w0 * b0.w + w1 * b1v.w + w2 * b2v.w);
      *(f16x8*)(xr + col) = o;
    }
  }
  __syncthreads();

  // ======================= Phase B: MLP via f16 MFMA ========================
  // M=64 rows; wave w owns output cols [w*32,+32) in L1/L2, [w*16,+16) in L3.
  const int l16 = r & 15, quad = r >> 4;
  const int nb = w * 32;

  // ---- Layer 1: H1 = relu(X @ W1 + b1), K=384.
  // kc<128: A-frags straight from f1 (f32 global, 16 rows x 128B per group,
  // L2-friendly) with the same f32->f16 cast as the old staged copy.
  f32x4 acc[4][2];
  #pragma unroll
  for (int i = 0; i < 4; ++i)
    #pragma unroll
    for (int j = 0; j < 2; ++j) acc[i][j] = f32x4{0.f, 0.f, 0.f, 0.f};

  #pragma unroll
  for (int kc = 0; kc < CIN; kc += 32) {
    f16x8 a[4];
    if (kc < C1) {
      #pragma unroll
      for (int i = 0; i < 4; ++i) {
        const float* p = f1 + (size_t)(qb + i * 16 + l16) * C1 + kc + quad * 8;
        float4 u0 = *(const float4*)p;
        float4 u1 = *(const float4*)(p + 4);
        a[i][0] = (f16)u0.x; a[i][1] = (f16)u0.y;
        a[i][2] = (f16)u0.z; a[i][3] = (f16)u0.w;
        a[i][4] = (f16)u1.x; a[i][5] = (f16)u1.y;
        a[i][6] = (f16)u1.z; a[i][7] = (f16)u1.w;
      }
    } else {
      #pragma unroll
      for (int i = 0; i < 4; ++i)
        a[i] = *(const f16x8*)(Xs + (i * 16 + l16) * XS_STRIDE +
                               (kc - C1) + quad * 8);
    }
    f16x8 b[2];
    #pragma unroll
    for (int j = 0; j < 2; ++j)
      b[j] = *((const f16x8*)g_w1p +
               (size_t)((kc >> 5) * 16 + (w * 2 + j)) * 64 + r);
    #pragma unroll
    for (int i = 0; i < 4; ++i)
      #pragma unroll
      for (int j = 0; j < 2; ++j)
        acc[i][j] = __builtin_amdgcn_mfma_f32_16x16x32_f16(a[i], b[j], acc[i][j], 0, 0, 0);
  }
  __syncthreads();                         // all Xs reads done before Hs overwrite
  #pragma unroll
  for (int j = 0; j < 2; ++j) {
    float bv = b1[nb + j * 16 + l16];
    #pragma unroll
    for (int i = 0; i < 4; ++i)
      #pragma unroll
      for (int e = 0; e < 4; ++e) {
        int row = i * 16 + quad * 4 + e;
        Hs[row * HS_STRIDE + nb + j * 16 + l16] =
            (f16)fmaxf(acc[i][j][e] + bv, 0.f);
      }
  }
  __syncthreads();

  // ---- Layer 2: H2 = relu(H1 @ W2 + b2), K=256
  f32x4 acc2[4][2];
  #pragma unroll
  for (int i = 0; i < 4; ++i)
    #pragma unroll
    for (int j = 0; j < 2; ++j) acc2[i][j] = f32x4{0.f, 0.f, 0.f, 0.f};

  #pragma unroll
  for (int kc = 0; kc < 256; kc += 32) {
    f16x8 a[4];
    #pragma unroll
    for (int i = 0; i < 4; ++i)
      a[i] = *(const f16x8*)(Hs + (i * 16 + l16) * HS_STRIDE + kc + quad * 8);
    f16x8 b[2];
    #pragma unroll
    for (int j = 0; j < 2; ++j)
      b[j] = *((const f16x8*)g_w2p +
               (size_t)((kc >> 5) * 16 + (w * 2 + j)) * 64 + r);
    #pragma unroll
    for (int i = 0; i < 4; ++i)
      #pragma unroll
      for (int j = 0; j < 2; ++j)
        acc2[i][j] = __builtin_amdgcn_mfma_f32_16x16x32_f16(a[i], b[j], acc2[i][j], 0, 0, 0);
  }
  __syncthreads();                         // all H1 reads done before overwrite
  #pragma unroll
  for (int j = 0; j < 2; ++j) {
    float bv = b2[nb + j * 16 + l16];
    #pragma unroll
    for (int i = 0; i < 4; ++i)
      #pragma unroll
      for (int e = 0; e < 4; ++e) {
        int row = i * 16 + quad * 4 + e;
        Hs[row * HS_STRIDE + nb + j * 16 + l16] =
            (f16)fmaxf(acc2[i][j][e] + bv, 0.f);
      }
  }
  __syncthreads();

  // ---- Layer 3: OUT = H2 @ W3 + b3, K=256 (wave owns 16 cols)
  const int nb3 = w * 16;
  f32x4 acc3[4];
  #pragma unroll
  for (int i = 0; i < 4; ++i) acc3[i] = f32x4{0.f, 0.f, 0.f, 0.f};

  #pragma unroll
  for (int kc = 0; kc < 256; kc += 32) {
    f16x8 a[4];
    #pragma unroll
    for (int i = 0; i < 4; ++i)
      a[i] = *(const f16x8*)(Hs + (i * 16 + l16) * HS_STRIDE + kc + quad * 8);
    f16x8 b;
    b = *((const f16x8*)g_w3p + (size_t)((kc >> 5) * 8 + w) * 64 + r);
    #pragma unroll
    for (int i = 0; i < 4; ++i)
      acc3[i] = __builtin_amdgcn_mfma_f32_16x16x32_f16(a[i], b, acc3[i], 0, 0, 0);
  }
  {
    int col = nb3 + l16;
    float bv = b3[col];
    #pragma unroll
    for (int i = 0; i < 4; ++i)
      #pragma unroll
      for (int e = 0; e < 4; ++e) {
        int row = i * 16 + quad * 4 + e;
        out[(size_t)(qb + row) * COUT + col] = acc3[i][e] + bv;
      }
  }
}

// ---------------------------------------------------------------------------
extern "C" void kernel_launch(void* const* d_in, const int* in_sizes, int n_in,
                              void* d_out, int out_size, void* d_ws, size_t ws_size,
                              hipStream_t stream)
{
  (void)out_size; (void)d_ws; (void)ws_size;
  static const int expect[10] = {196608, 49152, 8388608, 4194304,
                                 98304, 256, 65536, 256, 32768, 128};
  const void* p[10];
  bool ok = (n_in == 10);
  if (ok) {
    bool used[10] = {false};
    for (int e = 0; e < 10; ++e) {
      p[e] = nullptr;
      for (int i = 0; i < 10; ++i) {
        if (!used[i] && in_sizes[i] == expect[e]) {
          p[e] = d_in[i]; used[i] = true; break;
        }
      }
      if (!p[e]) { ok = false; break; }
    }
  }
  if (!ok)
    for (int e = 0; e < 10; ++e) p[e] = d_in[e < n_in ? e : (n_in - 1)];

  prep<<<256, 256, 0, stream>>>(
      (const float*)p[1], (const float*)p[4],
      (const float*)p[6], (const float*)p[8]);

  fused_fp<<<QT / 64, 512, 0, stream>>>(
      (const float*)p[0], (const float*)p[1],
      (const float*)p[2], (const float*)p[3],
      (const float*)p[4], (const float*)p[5],
      (const float*)p[6], (const float*)p[7],
      (const float*)p[8], (const float*)p[9],
      (float*)d_out);
}

// Round 10
// 213.941 us; speedup vs baseline: 1.1025x; 1.1025x over previous
//
#include <hip/hip_runtime.h>
#include <stdint.h>

// Problem constants (B=4, N=16384, NP=4096) — ALL TENSORS FLOAT32.
#define QT   65536
#define NPTS 4096
#define C1   128
#define C2   256
#define CIN  384
#define COUT 128

typedef _Float16 f16;
typedef __attribute__((ext_vector_type(8))) _Float16 f16x8;
typedef __attribute__((ext_vector_type(4))) float f32x4;

// Pre-packed (per-launch) weights, f16 in MFMA B-fragment order:
//   idx = ((kcb*NCB + cb)*64 + lane)*8 + e
//   holds W[(kcb*32 + (lane>>4)*8 + e) * N + cb*16 + (lane&15)]
// -> a wave's fragment (kcb, cb) is one contiguous 1KB block; lane reads
//    16B at lane*16 -> single global_load_dwordx4, L2-resident.
__device__ __attribute__((aligned(16))) f16 g_w1p[12 * 16 * 64 * 8];
__device__ __attribute__((aligned(16))) f16 g_w2p[8 * 16 * 64 * 8];
__device__ __attribute__((aligned(16))) f16 g_w3p[8 * 8 * 64 * 8];
// Candidate table: (x, y, z, |p|^2) per xyz2 point, per batch. 256 KB,
// L2-resident. Read via wave-uniform pointer in the scan (scalar pipe).
__device__ __attribute__((aligned(16))) float4 g_cand[4 * NPTS];

// packW4: one iteration packs 4 lanes (consecutive cols) of one fragment,
// reading float4 from W (coalesced within the 4-col group).
__device__ inline void packW4(const float* __restrict__ W, f16* __restrict__ dst,
                              int i, int N, int NCB) {
  const int g = i & 3, quad = (i >> 2) & 3, cbk = i >> 4;
  const int cb = cbk % NCB, kcb = cbk / NCB;
  const int col = cb * 16 + g * 4;
  const int k0 = kcb * 32 + quad * 8;
  f16x8 o[4];
#pragma unroll
  for (int e = 0; e < 8; ++e) {
    float4 v = *(const float4*)(W + (size_t)(k0 + e) * N + col);
    o[0][e] = (f16)v.x; o[1][e] = (f16)v.y; o[2][e] = (f16)v.z; o[3][e] = (f16)v.w;
  }
  f16* base = dst + ((size_t)cbk * 64 + quad * 16 + g * 4) * 8;
#pragma unroll
  for (int j = 0; j < 4; ++j) *(f16x8*)(base + j * 8) = o[j];
}

__global__ __launch_bounds__(256) void prep(
    const float* __restrict__ xyz2, const float* __restrict__ W1,
    const float* __restrict__ W2,   const float* __restrict__ W3) {
  const int tid = blockIdx.x * 256 + threadIdx.x;
  const int nthr = gridDim.x * 256;
  for (int i = tid; i < 4 * NPTS; i += nthr) {
    const float* p = xyz2 + (size_t)i * 3;
    float x = p[0], y = p[1], z = p[2];
    g_cand[i] = make_float4(x, y, z, fmaf(x, x, fmaf(y, y, z * z)));
  }
  for (int i = tid; i < 12 * 16 * 16; i += nthr) packW4(W1, g_w1p, i, 256, 16);
  for (int i = tid; i < 8 * 16 * 16; i += nthr) packW4(W2, g_w2p, i, 256, 16);
  for (int i = tid; i < 8 * 8 * 16; i += nthr) packW4(W3, g_w3p, i, 128, 8);
}

__device__ inline uint32_t umin(uint32_t a, uint32_t b) { return a < b ? a : b; }
__device__ inline uint32_t med3u(uint32_t a, uint32_t b, uint32_t c) {
  uint32_t d;
  asm("v_med3_u32 %0, %1, %2, %3" : "=v"(d) : "v"(a), "v"(b), "v"(c));
  return d;
}

// LDS overlay (phases strictly barrier-separated):
//  Phase A: dmpD f64[8][64][3]     @16384  (12288)  per-wave top-3 dists
//           dmpI i32[8][64][3]     @28672  (6144)   per-wave top-3 idx
//  persist: wv   f32[64][4]        @50176  (1024)
//           iv   i32[64][4]        @51200  (1024)   end 52224
//  Phase B: Xs f16[64][392]        @0      (50176)  (X = [f1|interp])
//           Hs f16[64][264]        @0      (33792)  (H1, then H2)
#define XS_STRIDE 392
#define HS_STRIDE 264
#define DMPD_OFF 16384
#define DMPI_OFF 28672
#define WV_OFF 50176
#define IV_OFF 51200
#define SMEM_BYTES 52224

__global__ __launch_bounds__(512) void fused_fp(
    const float* __restrict__ xyz1, const float* __restrict__ xyz2,
    const float* __restrict__ f1,   const float* __restrict__ f2,
    const float* __restrict__ W1,   const float* __restrict__ b1,
    const float* __restrict__ W2,   const float* __restrict__ b2,
    const float* __restrict__ W3,   const float* __restrict__ b3,
    float* __restrict__ out)
{
  __shared__ __align__(16) char smem[SMEM_BYTES];
  double*   dmpD = (double*)(smem + DMPD_OFF);  // [8][64][3]
  int*      dmpI = (int*)(smem + DMPI_OFF);     // [8][64][3]
  float*    wvp  = (float*)(smem + WV_OFF);     // [64][4]
  int*      ivp  = (int*)(smem + IV_OFF);       // [64][4]
  f16*      Xs   = (f16*)smem;                  // [64][XS_STRIDE]
  f16*      Hs   = (f16*)smem;                  // [64][HS_STRIDE]

  const int t = threadIdx.x;
  const int r = t & 63;              // query row within block / lane id
  const int w = t >> 6;              // wave id 0..7
  const int qb = blockIdx.x * 64;
  const int batch = qb >> 14;        // 16384 queries per batch
  const float* xz2b = xyz2 + (size_t)batch * NPTS * 3;
  const float* f2b  = f2   + (size_t)batch * NPTS * C2;

  // ======================= Phase A: exact 3-NN =======================
  // Per-lane top-5 of packed keys over this wave's 512-candidate slice:
  //   e   = fma(nx,cx, fma(ny,cy, fma(nz,cz, |p|^2 + (|q|^2+0.05))))
  //   key = (bits(e) & 0xFFFFF000) | idx
  // The inner |p|^2+sbias add is one v_add_f32 (SGPR+VGPR) replacing the
  // forced s->v mov (two-SGPR fma operand) AND the trailing add: -1 VALU op
  // per candidate vs r8. e > 0 always (bias dominates rounding), so u32
  // order == float order. 12 dropped mantissa bits = 4.9e-4 relative
  // quantization, absorbed by depth-5 margin + exact f64 rescore (proven
  // r2/r6/r8).
  const int q = qb + r;
  const float qx = xyz1[q * 3], qy = xyz1[q * 3 + 1], qz = xyz1[q * 3 + 2];
  const float nx = -2.f * qx, ny = -2.f * qy, nz = -2.f * qz;
  const float sq1q = qx * qx + qy * qy + qz * qz;

  uint32_t k0 = ~0u, k1 = ~0u, k2 = ~0u, k3 = ~0u, k4 = ~0u;

  auto ins5 = [&](uint32_t c) {
    uint32_t n0 = umin(k0, c);
    uint32_t n1 = med3u(k0, k1, c);
    uint32_t n2 = med3u(k1, k2, c);
    uint32_t n3 = med3u(k2, k3, c);
    uint32_t n4 = med3u(k3, k4, c);
    k0 = n0; k1 = n1; k2 = n2; k3 = n3; k4 = n4;
  };
  auto packk = [&](float e, uint32_t idx) -> uint32_t {
    return (__builtin_bit_cast(uint32_t, e) & 0xFFFFF000u) | idx;
  };

  {
    const int wu = __builtin_amdgcn_readfirstlane(w);   // force SGPR-uniform
    const float4* __restrict__ cp = g_cand + (batch << 12) + (wu << 9);
    const uint32_t abase = (uint32_t)(wu << 9);
    const float sbias = sq1q + 0.05f;
    #pragma unroll 2
    for (int m = 0; m < 512; m += 4) {
      float4 c0 = cp[m], c1 = cp[m + 1], c2 = cp[m + 2], c3 = cp[m + 3];
      float e0 = fmaf(nx, c0.x, fmaf(ny, c0.y, fmaf(nz, c0.z, c0.w + sbias)));
      float e1 = fmaf(nx, c1.x, fmaf(ny, c1.y, fmaf(nz, c1.z, c1.w + sbias)));
      float e2 = fmaf(nx, c2.x, fmaf(ny, c2.y, fmaf(nz, c2.z, c2.w + sbias)));
      float e3 = fmaf(nx, c3.x, fmaf(ny, c3.y, fmaf(nz, c3.z, c3.w + sbias)));
      ins5(packk(e0, abase + m));
      ins5(packk(e1, abase + m + 1));
      ins5(packk(e2, abase + m + 2));
      ins5(packk(e3, abase + m + 3));
    }
  }

  // ---- Stage 1 (ALL waves, parallel): exact f64 rescore of this wave's
  // own 5 register-held survivors -> per-wave top-3 (d, idx), total order
  // (d, then low idx).
  {
    const double x1 = (double)qx, y1 = (double)qy, z1 = (double)qz;
    const double sq1 = x1 * x1 + y1 * y1 + z1 * z1;
    double d0 = 1e300, d1 = 1e300, d2 = 1e300;
    int j0 = 0, j1 = 0, j2 = 0;
    uint32_t sv[5] = {k0, k1, k2, k3, k4};
    #pragma unroll
    for (int s = 0; s < 5; ++s) {
      int idx = (int)(sv[s] & (NPTS - 1));
      const float* p2 = xz2b + (size_t)idx * 3;
      double x2 = (double)p2[0], y2 = (double)p2[1], z2 = (double)p2[2];
      double d = sq1 + (x2 * x2 + y2 * y2 + z2 * z2)
                     - 2.0 * (x1 * x2 + y1 * y2 + z1 * z2);
      bool c2 = (d < d2) || (d == d2 && idx < j2);
      bool c1 = (d < d1) || (d == d1 && idx < j1);
      bool c0 = (d < d0) || (d == d0 && idx < j0);
      d2 = c1 ? d1 : (c2 ? d : d2);  j2 = c1 ? j1 : (c2 ? idx : j2);
      d1 = c0 ? d0 : (c1 ? d : d1);  j1 = c0 ? j0 : (c1 ? idx : j1);
      d0 = c0 ? d : d0;              j0 = c0 ? idx : j0;
    }
    const int base = (w * 64 + r) * 3;
    dmpD[base]     = d0;  dmpI[base]     = j0;
    dmpD[base + 1] = d1;  dmpI[base + 1] = j1;
    dmpD[base + 2] = d2;  dmpI[base + 2] = j2;
  }
  __syncthreads();

  // ---- Stage 2 (wave 0): merge the 24 (d, idx) pairs from LDS (no global
  // loads, no recompute). top3(union) == top3(union of per-group top3) under
  // the same total order -> bit-identical to the single-stage 40-rescore.
  if (w == 0) {
    double d0 = 1e300, d1 = 1e300, d2 = 1e300;
    int j0 = 0, j1 = 0, j2 = 0;
    #pragma unroll
    for (int w2 = 0; w2 < 8; ++w2) {
      #pragma unroll
      for (int s = 0; s < 3; ++s) {
        const int base = (w2 * 64 + r) * 3 + s;
        double d = dmpD[base];
        int idx  = dmpI[base];
        bool c2 = (d < d2) || (d == d2 && idx < j2);
        bool c1 = (d < d1) || (d == d1 && idx < j1);
        bool c0 = (d < d0) || (d == d0 && idx < j0);
        d2 = c1 ? d1 : (c2 ? d : d2);  j2 = c1 ? j1 : (c2 ? idx : j2);
        d1 = c0 ? d0 : (c1 ? d : d1);  j1 = c0 ? j0 : (c1 ? idx : j1);
        d0 = c0 ? d : d0;              j0 = c0 ? idx : j0;
      }
    }
    float e0 = fmaxf((float)d0, 1e-10f);
    float e1 = fmaxf((float)d1, 1e-10f);
    float e2 = fmaxf((float)d2, 1e-10f);
    float r0 = 1.f / e0, r1 = 1.f / e1, r2 = 1.f / e2;
    float inv = 1.f / (r0 + r1 + r2);
    wvp[r * 4 + 0] = r0 * inv; wvp[r * 4 + 1] = r1 * inv;
    wvp[r * 4 + 2] = r2 * inv; wvp[r * 4 + 3] = 0.f;
    ivp[r * 4 + 0] = j0; ivp[r * 4 + 1] = j1; ivp[r * 4 + 2] = j2; ivp[r * 4 + 3] = 0;
  }
  __syncthreads();

  // ============ Build X = [f1 | interp] once per block (f16 in LDS) ============
  // 8 threads per row. f1: direct f32 load + cast. Interp: f32 weighted sum,
  // then one f16 cast — identical numerics to r2/r6/r8 (passing).
  {
    const int row = t >> 3, c = t & 7;
    f16* xr = Xs + row * XS_STRIDE;
    {
      const float* f1r = f1 + (size_t)(qb + row) * C1 + c * 16;
      float4 u0 = *(const float4*)(f1r);
      float4 u1 = *(const float4*)(f1r + 4);
      float4 u2 = *(const float4*)(f1r + 8);
      float4 u3 = *(const float4*)(f1r + 12);
      f16x8 o0, o1;
      o0[0] = (f16)u0.x; o0[1] = (f16)u0.y; o0[2] = (f16)u0.z; o0[3] = (f16)u0.w;
      o0[4] = (f16)u1.x; o0[5] = (f16)u1.y; o0[6] = (f16)u1.z; o0[7] = (f16)u1.w;
      o1[0] = (f16)u2.x; o1[1] = (f16)u2.y; o1[2] = (f16)u2.z; o1[3] = (f16)u2.w;
      o1[4] = (f16)u3.x; o1[5] = (f16)u3.y; o1[6] = (f16)u3.z; o1[7] = (f16)u3.w;
      *(f16x8*)(xr + c * 16)     = o0;
      *(f16x8*)(xr + c * 16 + 8) = o1;
    }
    const float w0 = wvp[row * 4 + 0], w1 = wvp[row * 4 + 1], w2 = wvp[row * 4 + 2];
    const float* p0 = f2b + (size_t)(ivp[row * 4 + 0] & (NPTS - 1)) * C2;
    const float* p1 = f2b + (size_t)(ivp[row * 4 + 1] & (NPTS - 1)) * C2;
    const float* p2 = f2b + (size_t)(ivp[row * 4 + 2] & (NPTS - 1)) * C2;
    #pragma unroll
    for (int ch = 0; ch < 4; ++ch) {
      const int col = ch * 64 + c * 8;
      float4 a0 = *(const float4*)(p0 + col), b0 = *(const float4*)(p0 + col + 4);
      float4 a1 = *(const float4*)(p1 + col), b1v = *(const float4*)(p1 + col + 4);
      float4 a2 = *(const float4*)(p2 + col), b2v = *(const float4*)(p2 + col + 4);
      f16x8 o;
      o[0] = (f16)(w0 * a0.x + w1 * a1.x + w2 * a2.x);
      o[1] = (f16)(w0 * a0.y + w1 * a1.y + w2 * a2.y);
      o[2] = (f16)(w0 * a0.z + w1 * a1.z + w2 * a2.z);
      o[3] = (f16)(w0 * a0.w + w1 * a1.w + w2 * a2.w);
      o[4] = (f16)(w0 * b0.x + w1 * b1v.x + w2 * b2v.x);
      o[5] = (f16)(w0 * b0.y + w1 * b1v.y + w2 * b2v.y);
      o[6] = (f16)(w0 * b0.z + w1 * b1v.z + w2 * b2v.z);
      o[7] = (f16)(w0 * b0.w + w1 * b1v.w + w2 * b2v.w);
      *(f16x8*)(xr + C1 + col) = o;
    }
  }
  __syncthreads();

  // ======================= Phase B: MLP via f16 MFMA ========================
  // M=64 rows; wave w owns output cols [w*32,+32) in L1/L2, [w*16,+16) in L3.
  const int l16 = r & 15, quad = r >> 4;
  const int nb = w * 32;

  // ---- Layer 1: H1 = relu(X @ W1 + b1), K=384
  f32x4 acc[4][2];
  #pragma unroll
  for (int i = 0; i < 4; ++i)
    #pragma unroll
    for (int j = 0; j < 2; ++j) acc[i][j] = f32x4{0.f, 0.f, 0.f, 0.f};

  #pragma unroll
  for (int kc = 0; kc < CIN; kc += 32) {
    f16x8 a[4];
    #pragma unroll
    for (int i = 0; i < 4; ++i)
      a[i] = *(const f16x8*)(Xs + (i * 16 + l16) * XS_STRIDE + kc + quad * 8);
    f16x8 b[2];
    #pragma unroll
    for (int j = 0; j < 2; ++j)
      b[j] = *((const f16x8*)g_w1p +
               (size_t)((kc >> 5) * 16 + (w * 2 + j)) * 64 + r);
    #pragma unroll
    for (int i = 0; i < 4; ++i)
      #pragma unroll
      for (int j = 0; j < 2; ++j)
        acc[i][j] = __builtin_amdgcn_mfma_f32_16x16x32_f16(a[i], b[j], acc[i][j], 0, 0, 0);
  }
  __syncthreads();                         // all Xs reads done before Hs overwrite
  #pragma unroll
  for (int j = 0; j < 2; ++j) {
    float bv = b1[nb + j * 16 + l16];
    #pragma unroll
    for (int i = 0; i < 4; ++i)
      #pragma unroll
      for (int e = 0; e < 4; ++e) {
        int row = i * 16 + quad * 4 + e;
        Hs[row * HS_STRIDE + nb + j * 16 + l16] =
            (f16)fmaxf(acc[i][j][e] + bv, 0.f);
      }
  }
  __syncthreads();

  // ---- Layer 2: H2 = relu(H1 @ W2 + b2), K=256
  f32x4 acc2[4][2];
  #pragma unroll
  for (int i = 0; i < 4; ++i)
    #pragma unroll
    for (int j = 0; j < 2; ++j) acc2[i][j] = f32x4{0.f, 0.f, 0.f, 0.f};

  #pragma unroll
  for (int kc = 0; kc < 256; kc += 32) {
    f16x8 a[4];
    #pragma unroll
    for (int i = 0; i < 4; ++i)
      a[i] = *(const f16x8*)(Hs + (i * 16 + l16) * HS_STRIDE + kc + quad * 8);
    f16x8 b[2];
    #pragma unroll
    for (int j = 0; j < 2; ++j)
      b[j] = *((const f16x8*)g_w2p +
               (size_t)((kc >> 5) * 16 + (w * 2 + j)) * 64 + r);
    #pragma unroll
    for (int i = 0; i < 4; ++i)
      #pragma unroll
      for (int j = 0; j < 2; ++j)
        acc2[i][j] = __builtin_amdgcn_mfma_f32_16x16x32_f16(a[i], b[j], acc2[i][j], 0, 0, 0);
  }
  __syncthreads();                         // all H1 reads done before overwrite
  #pragma unroll
  for (int j = 0; j < 2; ++j) {
    float bv = b2[nb + j * 16 + l16];
    #pragma unroll
    for (int i = 0; i < 4; ++i)
      #pragma unroll
      for (int e = 0; e < 4; ++e) {
        int row = i * 16 + quad * 4 + e;
        Hs[row * HS_STRIDE + nb + j * 16 + l16] =
            (f16)fmaxf(acc2[i][j][e] + bv, 0.f);
      }
  }
  __syncthreads();

  // ---- Layer 3: OUT = H2 @ W3 + b3, K=256 (wave owns 16 cols)
  const int nb3 = w * 16;
  f32x4 acc3[4];
  #pragma unroll
  for (int i = 0; i < 4; ++i) acc3[i] = f32x4{0.f, 0.f, 0.f, 0.f};

  #pragma unroll
  for (int kc = 0; kc < 256; kc += 32) {
    f16x8 a[4];
    #pragma unroll
    for (int i = 0; i < 4; ++i)
      a[i] = *(const f16x8*)(Hs + (i * 16 + l16) * HS_STRIDE + kc + quad * 8);
    f16x8 b;
    b = *((const f16x8*)g_w3p + (size_t)((kc >> 5) * 8 + w) * 64 + r);
    #pragma unroll
    for (int i = 0; i < 4; ++i)
      acc3[i] = __builtin_amdgcn_mfma_f32_16x16x32_f16(a[i], b, acc3[i], 0, 0, 0);
  }
  {
    int col = nb3 + l16;
    float bv = b3[col];
    #pragma unroll
    for (int i = 0; i < 4; ++i)
      #pragma unroll
      for (int e = 0; e < 4; ++e) {
        int row = i * 16 + quad * 4 + e;
        out[(size_t)(qb + row) * COUT + col] = acc3[i][e] + bv;
      }
  }
}

// ---------------------------------------------------------------------------
extern "C" void kernel_launch(void* const* d_in, const int* in_sizes, int n_in,
                              void* d_out, int out_size, void* d_ws, size_t ws_size,
                              hipStream_t stream)
{
  (void)out_size; (void)d_ws; (void)ws_size;
  static const int expect[10] = {196608, 49152, 8388608, 4194304,
                                 98304, 256, 65536, 256, 32768, 128};
  const void* p[10];
  bool ok = (n_in == 10);
  if (ok) {
    bool used[10] = {false};
    for (int e = 0; e < 10; ++e) {
      p[e] = nullptr;
      for (int i = 0; i < 10; ++i) {
        if (!used[i] && in_sizes[i] == expect[e]) {
          p[e] = d_in[i]; used[i] = true; break;
        }
      }
      if (!p[e]) { ok = false; break; }
    }
  }
  if (!ok)
    for (int e = 0; e < 10; ++e) p[e] = d_in[e < n_in ? e : (n_in - 1)];

  prep<<<256, 256, 0, stream>>>(
      (const float*)p[1], (const float*)p[4],
      (const float*)p[6], (const float*)p[8]);

  fused_fp<<<QT / 64, 512, 0, stream>>>(
      (const float*)p[0], (const float*)p[1],
      (const float*)p[2], (const float*)p[3],
      (const float*)p[4], (const float*)p[5],
      (const float*)p[6], (const float*)p[7],
      (const float*)p[8], (const float*)p[9],
      (float*)d_out);
}